// Round 8
// baseline (164.686 us; speedup 1.0000x reference)
//
#include <hip/hip_runtime.h>

// Problem constants
static constexpr int B_ = 64, A_ = 32, BOARD_ = 64, D_ = 5;
static constexpr long long FACN = (long long)B_ * A_ * BOARD_ * BOARD_ * D_; // 41,943,040
static constexpr long long CHN  = (long long)B_ * A_ * BOARD_ * BOARD_;      // 8,388,608
static constexpr int NAG = B_ * A_;                                          // 2048

// exp(-1/50), exp(-1/20)
static constexpr float FAC_DECAY = 0.9801986733067553f;
static constexpr float INH_DECAY = 0.9512294245007140f;

// Native clang vector type — required by __builtin_nontemporal_load/store.
typedef float f32x4 __attribute__((ext_vector_type(4)));

// Bulk streaming decay: out[fac | inh | ch] = in * scale.
// SINGLE-VARIABLE EXPERIMENT vs r7: 512 blocks instead of 2048 (2 blocks/CU,
// 8 waves/CU). Rationale: harness fill kernels hit 7.0 TB/s at ~10% occupancy
// -> few long sequential DRAM streams beat many interleaved ones. Each block
// owns a contiguous 45056-vector (704 KB) chunk; groups of 1024 keep the
// region pick wave-uniform; software pipeline (prefetch next group before
// storing current) keeps the read stream fed.
__global__ __launch_bounds__(256) void bulk_kernel(
    const f32x4* __restrict__ fac_in, const f32x4* __restrict__ inh_in,
    const f32x4* __restrict__ ch_in, f32x4* __restrict__ out)
{
    const int FACV = (int)(FACN / 4);       // 10,485,760 vectors (= 10240*1024)
    const int C = 45056;                    // vectors per block (= 44*1024); 512*C = TOT
    const int t = threadIdx.x;
    const int base = blockIdx.x * C;

    auto ldgrp = [&](int G, f32x4 v[4], float& c) {
        const f32x4* __restrict__ s;
        if (G < FACV)          { s = fac_in + G;             c = FAC_DECAY; }
        else if (G < 2 * FACV) { s = inh_in + (G - FACV);    c = INH_DECAY; }
        else                   { s = ch_in + (G - 2 * FACV); c = 0.9f; }
        v[0] = __builtin_nontemporal_load(&s[t]);
        v[1] = __builtin_nontemporal_load(&s[t + 256]);
        v[2] = __builtin_nontemporal_load(&s[t + 512]);
        v[3] = __builtin_nontemporal_load(&s[t + 768]);
    };

    f32x4 v[4]; float c;
    ldgrp(base, v, c);
    int off = 0;
    while (true) {
        f32x4 w[4]; float c2;
        const int noff = off + 1024;
        if (noff < C) ldgrp(base + noff, w, c2);   // prefetch next group first
        f32x4* __restrict__ d = out + base + off;
        __builtin_nontemporal_store(v[0] * c, &d[t]);
        __builtin_nontemporal_store(v[1] * c, &d[t + 256]);
        __builtin_nontemporal_store(v[2] * c, &d[t + 512]);
        __builtin_nontemporal_store(v[3] * c, &d[t + 768]);
        if (noff >= C) break;
        v[0] = w[0]; v[1] = w[1]; v[2] = w[2]; v[3] = w[3]; c = c2;
        off = noff;
    }
}

// Per-agent tail, 8 threads per agent (d-slot split) -> 16384 threads.
// The scatter index (b,a,y,x) is unique per (b,a) -> no atomics; this kernel
// runs after bulk_kernel (stream-ordered) and overwrites the scattered cells
// with values computed from the ORIGINAL inputs.
// Slots d=0..4: fac/inh cell d. Slot d=5: ch cell + safety. d=6,7: idle.
// The collisions-dtype sniff is per-block parallel (reads 2048 bytes = the
// smallest possible encoding of the 2048-entry bool buffer -> always in bounds).
__global__ __launch_bounds__(64) void agent_kernel(
    const float* __restrict__ pos, const float* __restrict__ goal,
    const float* __restrict__ spike,
    const float* __restrict__ fac_in, const float* __restrict__ inh_in,
    const float* __restrict__ ch_in,
    const void* __restrict__ coll,
    float* __restrict__ out)
{
    // ---- parallel dtype sniff (benign-race shared flags) ----
    __shared__ int s_w4, s_h2;
    if (threadIdx.x == 0) { s_w4 = 1; s_h2 = 1; }
    __syncthreads();
    {
        const unsigned int* cw = (const unsigned int*)coll;
        for (int k = threadIdx.x; k < 512; k += 64) {
            unsigned int w = cw[k];
            if (!(w == 0u || w == 1u || w == 0x3F800000u)) s_w4 = 0;
            unsigned int lo = w & 0xFFFFu, hi = w >> 16;
            if (!((lo == 0u || lo == 1u || lo == 0x3F80u || lo == 0x3C00u) &&
                  (hi == 0u || hi == 1u || hi == 0x3F80u || hi == 0x3C00u)))
                s_h2 = 0;
        }
    }
    __syncthreads();
    const int f = s_w4 ? 4 : (s_h2 ? 2 : 1);

    const int tid = blockIdx.x * 64 + threadIdx.x;
    const int idx = tid >> 3;          // agent
    const int d   = tid & 7;           // slot
    if (idx >= NAG || d >= 6) return;

    float px = pos[idx * 2 + 0];
    float py = pos[idx * 2 + 1];
    int x = min(BOARD_ - 1, max(0, (int)px));   // trunc like .astype(int32); pos >= 0
    int y = min(BOARD_ - 1, max(0, (int)py));
    long long cell = ((long long)idx * BOARD_ + y) * BOARD_ + x;

    bool c;
    if (f == 4)      c = ((const unsigned int*)coll)[idx] != 0u;
    else if (f == 2) c = ((const unsigned short*)coll)[idx] != 0u;
    else             c = ((const unsigned char*)coll)[idx] != 0u;

    float chv = ch_in[cell] * 0.9f + (c ? 0.1f : 0.0f);
    float safety = 1.0f - fminf(fmaxf(chv, 0.0f), 1.0f);

    if (d == 5) {
        const long long CHOFF  = 2 * FACN;
        const long long SAFOFF = CHOFF + CHN;
        out[CHOFF + cell] = chv;
        out[SAFOFF + idx] = safety;
        return;
    }

    bool safe = safety > 0.7f;

    // goal alignment for this direction: (gn . delta[d] + 1) / 2
    float gx = goal[idx * 2 + 0] - px;
    float gy = goal[idx * 2 + 1] - py;
    float n = sqrtf(gx * gx + gy * gy) + 1e-8f;
    float gnx = gx / n, gny = gy / n;
    float al = (d == 0) ? 0.5f
             : (d == 1) ? (gnx + 1.0f) * 0.5f
             : (d == 2) ? (gny + 1.0f) * 0.5f
             : (d == 3) ? (1.0f - gnx) * 0.5f
                        : (1.0f - gny) * 0.5f;

    long long cd = cell * D_ + d;
    bool sp = spike[idx * D_ + d] > 0.5f;
    bool fc = sp && safe && (al > 0.6f);
    bool ic = sp && (!safe || (al <= 0.4f));
    out[cd]        = fac_in[cd] * FAC_DECAY + (fc ? 0.0002f : 0.0f);
    out[FACN + cd] = inh_in[cd] * INH_DECAY + (ic ? 0.0001f : 0.0f);
}

extern "C" void kernel_launch(void* const* d_in, const int* in_sizes, int n_in,
                              void* d_out, int out_size, void* d_ws, size_t ws_size,
                              hipStream_t stream) {
    const float* pos   = (const float*)d_in[0];
    const float* goal  = (const float*)d_in[1];
    const float* spike = (const float*)d_in[2];
    const float* fac   = (const float*)d_in[3];
    const float* inh   = (const float*)d_in[4];
    const float* ch    = (const float*)d_in[5];
    const void*  coll  = d_in[6];
    float* out = (float*)d_out;

    hipLaunchKernelGGL(bulk_kernel, dim3(512), dim3(256), 0, stream,
                       (const f32x4*)fac, (const f32x4*)inh, (const f32x4*)ch, (f32x4*)out);
    hipLaunchKernelGGL(agent_kernel, dim3(256), dim3(64), 0, stream,
                       pos, goal, spike, fac, inh, ch, coll, out);
}

// Round 9
// 142.486 us; speedup vs baseline: 1.1558x; 1.1558x over previous
//
#include <hip/hip_runtime.h>

// Problem constants
static constexpr int B_ = 64, A_ = 32, BOARD_ = 64, D_ = 5;
static constexpr long long FACN = (long long)B_ * A_ * BOARD_ * BOARD_ * D_; // 41,943,040 floats
static constexpr long long CHN  = (long long)B_ * A_ * BOARD_ * BOARD_;      //  8,388,608 floats
static constexpr int NAG = B_ * A_;                                          // 2048 agents
static constexpr int SL  = BOARD_ * BOARD_ * D_;                             // 20480 floats / agent fac slab
static constexpr int SLC = BOARD_ * BOARD_;                                  //  4096 floats / agent ch slab

// exp(-1/50), exp(-1/20)
static constexpr float FAC_DECAY = 0.9801986733067553f;
static constexpr float INH_DECAY = 0.9512294245007140f;

typedef float f32x4 __attribute__((ext_vector_type(4)));

// Fully fused kernel. 2048 blocks x 256 threads (r7's best bulk config).
//
// Phase 1 (streaming): block b owns contiguous vectors [b*11264, (b+1)*11264)
// of out = [fac | inh | ch]; group starts & region boundaries are multiples of
// 1024 vectors -> wave-uniform region pick; software-pipelined (prefetch next
// group before storing current); nontemporal both ways.
//
// Phase 2 (corrections): after __syncthreads (orders the block's own stores),
// overwrite the agent-scatter cells that fall inside THIS block's float range
// [b*45056, (b+1)*45056) with values computed from the ORIGINAL inputs.
// Each out-float has exactly one writer block -> no cross-block race; agents
// whose 5-float cell straddles a chunk boundary are fixed per-float by each
// owning block (both compute identical values). Block b also writes safety[b]
// (safety floats lie past all chunks). Deterministic -> graph-replay safe.
__global__ __launch_bounds__(256) void fused_kernel(
    const f32x4* __restrict__ fac4, const f32x4* __restrict__ inh4,
    const f32x4* __restrict__ ch4, f32x4* __restrict__ out4,
    const float* __restrict__ pos, const float* __restrict__ goal,
    const float* __restrict__ spike,
    const float* __restrict__ fac_in, const float* __restrict__ inh_in,
    const float* __restrict__ ch_in,
    const void* __restrict__ coll,
    float* __restrict__ out)
{
    const int FACV = (int)(FACN / 4);       // 10,485,760 vectors (= 10240*1024)
    const int C = 11264;                    // vectors per block (11*1024); 2048*C = total
    const int t = threadIdx.x;
    const int bid = blockIdx.x;
    const int base = bid * C;

    __shared__ int s_w4, s_h2;
    if (t == 0) { s_w4 = 1; s_h2 = 1; }
    __syncthreads();

    // ---- Phase 1: streaming decay ----
    auto ldgrp = [&](int G, f32x4 v[4], float& c) {
        const f32x4* __restrict__ s;
        if (G < FACV)          { s = fac4 + G;             c = FAC_DECAY; }
        else if (G < 2 * FACV) { s = inh4 + (G - FACV);    c = INH_DECAY; }
        else                   { s = ch4 + (G - 2 * FACV); c = 0.9f; }
        v[0] = __builtin_nontemporal_load(&s[t]);
        v[1] = __builtin_nontemporal_load(&s[t + 256]);
        v[2] = __builtin_nontemporal_load(&s[t + 512]);
        v[3] = __builtin_nontemporal_load(&s[t + 768]);
    };

    {
        f32x4 v[4]; float c;
        ldgrp(base, v, c);
        int off = 0;
        while (true) {
            f32x4 w[4]; float c2;
            const int noff = off + 1024;
            if (noff < C) ldgrp(base + noff, w, c2);   // prefetch next group first
            f32x4* __restrict__ d = out4 + base + off;
            __builtin_nontemporal_store(v[0] * c, &d[t]);
            __builtin_nontemporal_store(v[1] * c, &d[t + 256]);
            __builtin_nontemporal_store(v[2] * c, &d[t + 512]);
            __builtin_nontemporal_store(v[3] * c, &d[t + 768]);
            if (noff >= C) break;
            v[0] = w[0]; v[1] = w[1]; v[2] = w[2]; v[3] = w[3]; c = c2;
            off = noff;
        }
    }

    // ---- collisions-dtype sniff (2048 bytes = smallest possible encoding) ----
    {
        const unsigned int* cw = (const unsigned int*)coll;
        for (int k = t; k < 512; k += 256) {
            unsigned int w = cw[k];
            if (!(w == 0u || w == 1u || w == 0x3F800000u)) s_w4 = 0;
            unsigned int lo = w & 0xFFFFu, hi = w >> 16;
            if (!((lo == 0u || lo == 1u || lo == 0x3F80u || lo == 0x3C00u) &&
                  (hi == 0u || hi == 1u || hi == 0x3F80u || hi == 0x3C00u)))
                s_h2 = 0;
        }
    }
    __threadfence_block();
    __syncthreads();   // streaming stores of this block complete & ordered; sniff flags ready
    const int f = s_w4 ? 4 : (s_h2 ? 2 : 1);

    // ---- Phase 2: chunk-local agent corrections ----
    const long long CF = 45056;             // floats per chunk (= C*4)
    const long long F0 = (long long)bid * CF, F1 = F0 + CF;

    auto fix_agent = [&](int ia, int region) {  // region 0=fac, 1=inh, 2=ch
        float px = pos[ia * 2 + 0];
        float py = pos[ia * 2 + 1];
        int x = min(BOARD_ - 1, max(0, (int)px));   // trunc like .astype(int32); pos >= 0
        int y = min(BOARD_ - 1, max(0, (int)py));
        int lcell = y * BOARD_ + x;                 // 0..4095

        bool c;
        if (f == 4)      c = ((const unsigned int*)coll)[ia] != 0u;
        else if (f == 2) c = ((const unsigned short*)coll)[ia] != 0u;
        else             c = ((const unsigned char*)coll)[ia] != 0u;

        float chv = ch_in[(long long)ia * SLC + lcell] * 0.9f + (c ? 0.1f : 0.0f);
        float safety = 1.0f - fminf(fmaxf(chv, 0.0f), 1.0f);

        if (region == 2) {
            long long fl = 2 * FACN + (long long)ia * SLC + lcell;
            if (fl >= F0 && fl < F1) out[fl] = chv;
            return;
        }

        bool safe = safety > 0.7f;
        float gx = goal[ia * 2 + 0] - px;
        float gy = goal[ia * 2 + 1] - py;
        float n = sqrtf(gx * gx + gy * gy) + 1e-8f;
        float gnx = gx / n, gny = gy / n;
        float align[5];
        align[0] = 0.5f;
        align[1] = (gnx + 1.0f) * 0.5f;
        align[2] = (gny + 1.0f) * 0.5f;
        align[3] = (1.0f - gnx) * 0.5f;
        align[4] = (1.0f - gny) * 0.5f;

        long long cdb = (long long)ia * SL + (long long)lcell * D_;  // within-region float base
#pragma unroll
        for (int d = 0; d < D_; ++d) {
            bool sp = spike[ia * D_ + d] > 0.5f;
            long long fl;
            float v;
            if (region == 0) {
                bool fc = sp && safe && (align[d] > 0.6f);
                v = fac_in[cdb + d] * FAC_DECAY + (fc ? 0.0002f : 0.0f);
                fl = cdb + d;
            } else {
                bool ic = sp && (!safe || (align[d] <= 0.4f));
                v = inh_in[cdb + d] * INH_DECAY + (ic ? 0.0001f : 0.0f);
                fl = FACN + cdb + d;
            }
            if (fl >= F0 && fl < F1) out[fl] = v;
        }
    };

    // fac region intersection: [F0, F1) ∩ [0, FACN)
    if (t < 4) {
        long long a1 = min(F1, FACN);
        if (F0 < a1) {
            int ia = (int)(F0 / SL) + t;
            int iaMax = (int)((a1 - 1) / SL);
            if (ia <= iaMax && ia < NAG) fix_agent(ia, 0);
        }
    }
    // inh region intersection: [F0, F1) ∩ [FACN, 2*FACN)
    else if (t >= 8 && t < 12) {
        long long b0 = max(F0, FACN), b1 = min(F1, 2 * FACN);
        if (b0 < b1) {
            int ia = (int)((b0 - FACN) / SL) + (t - 8);
            int iaMax = (int)((b1 - FACN - 1) / SL);
            if (ia <= iaMax && ia < NAG) fix_agent(ia, 1);
        }
    }
    // ch region intersection: [F0, F1) ∩ [2*FACN, 2*FACN+CHN)
    else if (t >= 16 && t < 32) {
        long long c0 = max(F0, 2 * FACN), c1 = min(F1, 2 * FACN + CHN);
        if (c0 < c1) {
            int ia = (int)((c0 - 2 * FACN) / SLC) + (t - 16);
            int iaMax = (int)((c1 - 2 * FACN - 1) / SLC);
            if (ia <= iaMax && ia < NAG) fix_agent(ia, 2);
        }
    }
    // safety: block bid writes agent bid (floats past all chunks; exactly one writer)
    else if (t == 40) {
        int ia = bid;
        float px = pos[ia * 2 + 0];
        float py = pos[ia * 2 + 1];
        int x = min(BOARD_ - 1, max(0, (int)px));
        int y = min(BOARD_ - 1, max(0, (int)py));
        int lcell = y * BOARD_ + x;
        bool c;
        if (f == 4)      c = ((const unsigned int*)coll)[ia] != 0u;
        else if (f == 2) c = ((const unsigned short*)coll)[ia] != 0u;
        else             c = ((const unsigned char*)coll)[ia] != 0u;
        float chv = ch_in[(long long)ia * SLC + lcell] * 0.9f + (c ? 0.1f : 0.0f);
        out[2 * FACN + CHN + ia] = 1.0f - fminf(fmaxf(chv, 0.0f), 1.0f);
    }
}

extern "C" void kernel_launch(void* const* d_in, const int* in_sizes, int n_in,
                              void* d_out, int out_size, void* d_ws, size_t ws_size,
                              hipStream_t stream) {
    const float* pos   = (const float*)d_in[0];
    const float* goal  = (const float*)d_in[1];
    const float* spike = (const float*)d_in[2];
    const float* fac   = (const float*)d_in[3];
    const float* inh   = (const float*)d_in[4];
    const float* ch    = (const float*)d_in[5];
    const void*  coll  = d_in[6];
    float* out = (float*)d_out;

    hipLaunchKernelGGL(fused_kernel, dim3(2048), dim3(256), 0, stream,
                       (const f32x4*)fac, (const f32x4*)inh, (const f32x4*)ch, (f32x4*)out,
                       pos, goal, spike, fac, inh, ch, coll, out);
}